// Round 21
// baseline (180.701 us; speedup 1.0000x reference)
//
#include <hip/hip_runtime.h>
#include <hip/hip_fp16.h>

// ---- problem constants (fixed by setup_inputs) ----
#define DIMH 64
#define NFEAT 11
#define EFEAT 5
#define NG   128
#define NPG  20
#define NNODES (NG*NPG)        // 2560
#define EPG  (NPG*(NPG-1))     // 380
#define NEDGES (NG*EPG)        // 48640
#define H1D  128
#define KTOT (H1D*DIMH)        // 8192
#define DEGV 19.0f
#define NCH  16                // part chunks (one per k-octet)

typedef __attribute__((ext_vector_type(8))) _Float16 f16x8;
typedef __attribute__((ext_vector_type(4))) float    f32x4;

// ---------------------------------------------------------------------------
// k_prep: prologue jobs (grid 1230).  (R20 champion, verbatim)
// ---------------------------------------------------------------------------
__global__ __launch_bounds__(256) void k_prep(
    const float* __restrict__ x, const float* __restrict__ lin0w,
    const float* __restrict__ lin0b,
    const float* __restrict__ ea, const float* __restrict__ nn1w,
    const float* __restrict__ nn1b,
    const float* __restrict__ nn2w, const float* __restrict__ nn2b,
    const float* __restrict__ rootw,
    const float* __restrict__ lwih, const float* __restrict__ lwhh,
    float* __restrict__ out, _Float16* __restrict__ h1c,
    _Float16* __restrict__ WT2, _Float16* __restrict__ WpT2,
    float* __restrict__ wab) {
  int b = blockIdx.x, t = threadIdx.x;
  if (b < 256) {
    int tid = b * 256 + t;                 // 0..65535
    int ko = tid >> 12, ks = (tid >> 8) & 15, nf = (tid >> 6) & 3, l = tid & 63;
    int i = ks * 4 + (l >> 4);
    int o = nf * 16 + (l & 15);
    const float* src = nn2w + (size_t)(ko * 8) * 4096 + i * 64 + o;
    f16x8 v;
#pragma unroll
    for (int j = 0; j < 8; ++j)
      v[j] = (_Float16)(src[(size_t)j * 4096] * (1.f / DEGV));
    *(f16x8*)(WT2 + (size_t)tid * 8) = v;
  } else if (b < 896) {
    int idx = (b - 256) * 256 + t;
    int n = idx >> 6, o = idx & 63;
    float acc = lin0b[o];
#pragma unroll
    for (int j = 0; j < NFEAT; ++j) acc += x[n * NFEAT + j] * lin0w[j * DIMH + o];
    out[idx] = fmaxf(acc, 0.f);
  } else if (b < 1086) {
    int e = (b - 896) * 256 + t;
    float ef[EFEAT];
#pragma unroll
    for (int f = 0; f < EFEAT; ++f) ef[f] = ea[e * EFEAT + f];
    for (int ko = 0; ko < 16; ++ko) {
      f16x8 hv;
#pragma unroll
      for (int j = 0; j < 8; ++j) {
        int k = ko * 8 + j;
        float acc = nn1b[k];
#pragma unroll
        for (int f = 0; f < EFEAT; ++f) acc += ef[f] * nn1w[f * H1D + k];
        hv[j] = (_Float16)fmaxf(acc, 0.f);
      }
      ((f16x8*)h1c)[(size_t)ko * NEDGES + e] = hv;
    }
  } else if (b < 1102) {
    int idx = (b - 1086) * 256 + t;      // 0..4095
    int jp = idx & 7, l = (idx >> 3) & 63, nf = (idx >> 9) & 3;
    int ks = (idx >> 11) & 1;
    int o = nf * 16 + (l & 15);
    int j = ks * 32 + (l >> 4) * 8 + jp;
    WpT2[idx] = (_Float16)(rootw[j * 64 + o] - nn2b[j * 64 + o] * (1.f / DEGV));
  } else {
    int idx = (b - 1102) * 256 + t;      // 0..32767
    int row = idx >> 7, col = idx & 127;
    float v = lwih[(size_t)row * 128 + col];
    if (col < 64) v += lwhh[(size_t)row * 64 + col];
    wab[idx] = v;
  }
}

// ---------------------------------------------------------------------------
// k_pg: fused P-build + MFMA GEMM.  block = (ko, g).
// R21 change: P-build reads h1 octets DIRECTLY FROM GLOBAL (wave-uniform
// addresses, one 16B L2 txn per load) — h1s LDS buffer and the staging
// barrier are gone; moves P-build pressure from the saturated LDS unit to
// the idle vector-memory path. Same arithmetic, same Ps layout.
// ---------------------------------------------------------------------------
__global__ __launch_bounds__(256, 4) void k_pg(const _Float16* __restrict__ h1c,
                                               const float* __restrict__ out,
                                               const _Float16* __restrict__ WT2,
                                               const _Float16* __restrict__ WpT2,
                                               const float* __restrict__ nn2b,
                                               const float* __restrict__ convb,
                                               float* __restrict__ bgc,
                                               _Float16* __restrict__ part) {
  int ko = blockIdx.x, g = blockIdx.y;
  int t = threadIdx.x;
  __shared__ alignas(16) _Float16 Ps[NPG][520];
  __shared__ float sgl[64];
  __shared__ alignas(16) _Float16 AoT[NPG][64];
  int i = t & 63, w = t >> 6;
  int la = i & 15, hi = i >> 4;
  int nf = w;                              // wave = output column block
  _Float16 xh[NPG];
  {
    float s = 0.f;
#pragma unroll
    for (int r = 0; r < NPG; ++r) {
      float xv = out[((size_t)g * NPG + r) * 64 + i];
      s += xv;
      xh[r] = (_Float16)xv;
    }
    if (ko == 0 && t < 64) sgl[t] = s;
  }
  if (ko == 0 && t < 64) {      // bgc = sg . b2/19 + convb  (same-wave LDS dep)
    float acc = convb[t];
    for (int ii = 0; ii < 64; ++ii)
      acc += sgl[ii] * nn2b[ii * 64 + t] * (1.f / DEGV);
    bgc[g * 64 + t] = acc;
  }
  {
    const f16x8* hsrc = (const f16x8*)h1c + ((size_t)ko * NEDGES + (size_t)g * EPG);
#pragma unroll
    for (int cc = 0; cc < 5; ++cc) {
      int c = w + cc * 4;
      f16x8 acc = {(_Float16)0.f, (_Float16)0.f, (_Float16)0.f, (_Float16)0.f,
                   (_Float16)0.f, (_Float16)0.f, (_Float16)0.f, (_Float16)0.f};
#pragma unroll
      for (int r = 0; r < NPG; ++r) {
        if (r == c) continue;                 // wave-uniform skip
        int el = r * 19 + c - (c > r ? 1 : 0);
        acc += hsrc[el] * xh[r];              // global b128, packed pk_fma
      }
      *(f16x8*)&Ps[c][i * 8] = acc;           // direct b128 store, no cvt
    }
  }
  __syncthreads();
  f32x4 acc0 = {0.f, 0.f, 0.f, 0.f};   // tile0: A rows la    (writes rows 0..3)
  f32x4 acc1 = {0.f, 0.f, 0.f, 0.f};   // tile1: A rows 4+la  (writes rows 4..19)
  const f16x8* B = (const f16x8*)WT2;
#pragma unroll
  for (int ks = 0; ks < 16; ++ks) {
    f16x8 b0 = B[(size_t)(((ko * 16 + ks) * 4 + nf) * 64 + i)];
    f16x8 a0 = *(const f16x8*)&Ps[la][(ks * 4 + hi) * 8];
    f16x8 a1 = *(const f16x8*)&Ps[4 + la][(ks * 4 + hi) * 8];
    acc0 = __builtin_amdgcn_mfma_f32_16x16x32_f16(a0, b0, acc0, 0, 0, 0);
    acc1 = __builtin_amdgcn_mfma_f32_16x16x32_f16(a1, b0, acc1, 0, 0, 0);
  }
  if (ko == 15) {               // fold root term: A = fp16(out rows), B = WpT2
    if (w == 0) {
#pragma unroll
      for (int r = 0; r < NPG; ++r) AoT[r][i] = xh[r];
    }
    __syncthreads();
    const f16x8* W2f = (const f16x8*)WpT2;
#pragma unroll
    for (int ks2 = 0; ks2 < 2; ++ks2) {
      f16x8 b0 = W2f[(size_t)((ks2 * 4 + nf) * 64 + i)];
      f16x8 a0 = *(const f16x8*)&AoT[la][ks2 * 32 + hi * 8];
      f16x8 a1 = *(const f16x8*)&AoT[4 + la][ks2 * 32 + hi * 8];
      acc0 = __builtin_amdgcn_mfma_f32_16x16x32_f16(a0, b0, acc0, 0, 0, 0);
      acc1 = __builtin_amdgcn_mfma_f32_16x16x32_f16(a1, b0, acc1, 0, 0, 0);
    }
  }
  if (hi == 0) {                // tile0: rows 0..3, cols nf*16+la
#pragma unroll
    for (int q = 0; q < 4; ++q) {
      size_t base = ((size_t)(g * NPG + q) * NCH + ko) * 64;
      part[base + nf * 16 + la] = (_Float16)acc0[q];
    }
  }
#pragma unroll
  for (int q = 0; q < 4; ++q) { // tile1: rows 4..19, cols nf*16+la
    int row = 4 + hi * 4 + q;
    size_t base = ((size_t)(g * NPG + row) * NCH + ko) * 64;
    part[base + nf * 16 + la] = (_Float16)acc1[q];
  }
}

// ---------------------------------------------------------------------------
// k_gru: fused part-reduce + GRU, split 2 blocks per graph (node-local).
// 256 blocks x 512 threads, 10 nodes each.  (R20 champion, verbatim)
// ---------------------------------------------------------------------------
#define NLOC 10
__global__ __launch_bounds__(512, 1) void k_gru(
    const _Float16* __restrict__ part, const float* __restrict__ bgc,
    const float* __restrict__ wih, const float* __restrict__ whh,
    const float* __restrict__ bih, const float* __restrict__ bhh,
    float* __restrict__ out) {
  __shared__ float outs[NLOC][64];
  __shared__ float ms[NLOC][64];
  __shared__ float gi_s[NLOC][192];
  __shared__ float gh_s[NLOC][192];
  int t = threadIdx.x;
  int b = blockIdx.x, g = b >> 1, nbase = (b & 1) * NLOC;
  int role = (t < 192) ? 0 : ((t >= 256 && t < 448) ? 1 : -1);
  int r = (t < 192) ? t : t - 256;
  float4 wreg[16];
  if (role == 0) {
    const float4* src = (const float4*)(wih + (size_t)r * 64);
#pragma unroll
    for (int q = 0; q < 16; ++q) wreg[q] = src[q];
  } else if (role == 1) {
    const float4* src = (const float4*)(whh + (size_t)r * 64);
#pragma unroll
    for (int q = 0; q < 16; ++q) wreg[q] = src[q];
  }
  if (t < NLOC * 16)
    ((float4*)&outs[0][0])[t] =
        ((const float4*)(out + ((size_t)g * NPG + nbase) * 64))[t];
  __syncthreads();
  int o = t & 63, n0 = t >> 6;
  {
    float base = bgc[g * 64 + o];
#pragma unroll
    for (int k = 0; k < 2; ++k) {
      int n = n0 + k * 8;
      if (n < NLOC) {
        float a = base;
#pragma unroll
        for (int c = 0; c < NCH; ++c)
          a += (float)part[((size_t)(g * NPG + nbase + n) * NCH + c) * 64 + o];
        ms[n][o] = fmaxf(a, 0.f);
      }
    }
  }
  __syncthreads();
  if (role == 0) {
    for (int n = 0; n < NLOC; ++n) {
      float acc = 0.f;
#pragma unroll
      for (int q = 0; q < 16; ++q) {
        float4 xv = *(const float4*)&ms[n][q * 4];
        acc += wreg[q].x * xv.x + wreg[q].y * xv.y +
               wreg[q].z * xv.z + wreg[q].w * xv.w;
      }
      gi_s[n][r] = acc;
    }
  } else if (role == 1) {
    for (int n = 0; n < NLOC; ++n) {
      float acc = 0.f;
#pragma unroll
      for (int q = 0; q < 16; ++q) {
        float4 xv = *(const float4*)&outs[n][q * 4];
        acc += wreg[q].x * xv.x + wreg[q].y * xv.y +
               wreg[q].z * xv.z + wreg[q].w * xv.w;
      }
      gh_s[n][r] = acc;
    }
  }
  __syncthreads();
  {
    float bir = bih[o], biz = bih[64 + o], bin = bih[128 + o];
    float bhr = bhh[o], bhz = bhh[64 + o], bhn = bhh[128 + o];
#pragma unroll
    for (int k = 0; k < 2; ++k) {
      int n = n0 + k * 8;
      if (n < NLOC) {
        float rr = 1.f / (1.f + expf(-(gi_s[n][o] + bir + gh_s[n][o] + bhr)));
        float zz = 1.f / (1.f + expf(-(gi_s[n][64 + o] + biz +
                                       gh_s[n][64 + o] + bhz)));
        float nc = tanhf(gi_s[n][128 + o] + bin +
                         rr * (gh_s[n][128 + o] + bhn));
        out[((size_t)g * NPG + nbase + n) * DIMH + o] =
            (1.f - zz) * nc + zz * outs[n][o];
      }
    }
  }
}

// ---------------------------------------------------------------------------
// k_s2s: Set2Set (3 steps) + final MLP, 256 threads / graph.
// (R20 champion, verbatim)
// ---------------------------------------------------------------------------
__global__ __launch_bounds__(256) void k_s2s(
    const float* __restrict__ hn,
    const float* __restrict__ wab,
    const float* __restrict__ lbih, const float* __restrict__ lbhh,
    const float* __restrict__ l1w, const float* __restrict__ l1b,
    const float* __restrict__ l2w, const float* __restrict__ l2b,
    float* __restrict__ y) {
  int g = blockIdx.x, t = threadIdx.x;
  __shared__ float hs[NPG][DIMH];
  __shared__ float qstar[2 * DIMH];
  __shared__ float hls[DIMH];
  __shared__ float es_s[NPG];
  __shared__ float gates_s[4][DIMH];
  for (int idx = t; idx < NPG * 16; idx += 256)
    ((float4*)&hs[0][0])[idx] = ((const float4*)(hn + (size_t)g * NPG * 64))[idx];
  if (t < 128) qstar[t] = 0.f;
  if (t < 64) hls[t] = 0.f;
  float cl = 0.f;
  __syncthreads();
  int q = t >> 6, o = t & 63;
  const float4* wa = (const float4*)(wab + (size_t)(q * 64 + o) * 128);
  float bsum = lbih[q * 64 + o] + lbhh[q * 64 + o];
  for (int step = 0; step < 3; ++step) {
    {
      float acc = bsum;
      if (step > 0) {            // step 0: qstar = hls = 0 -> dots vanish
#pragma unroll
        for (int j4 = 0; j4 < 16; ++j4) {       // (Wih[:,:64]+Whh) . hl
          float4 w = wa[j4];
          float4 xv = *(const float4*)&hls[j4 * 4];
          acc += w.x * xv.x + w.y * xv.y + w.z * xv.z + w.w * xv.w;
        }
#pragma unroll
        for (int j4 = 0; j4 < 16; ++j4) {       // Wih[:,64:] . rvec
          float4 w = wa[16 + j4];
          float4 xv = *(const float4*)&qstar[DIMH + j4 * 4];
          acc += w.x * xv.x + w.y * xv.y + w.z * xv.z + w.w * xv.w;
        }
      }
      gates_s[q][o] = acc;
    }
    __syncthreads();
    if (t < 64) {
      float gi = gates_s[0][t], gf = gates_s[1][t];
      float gg = gates_s[2][t], go = gates_s[3][t];
      cl = 1.f / (1.f + expf(-gf)) * cl + 1.f / (1.f + expf(-gi)) * tanhf(gg);
      float hv = 1.f / (1.f + expf(-go)) * tanhf(cl);
      hls[t] = hv; qstar[t] = hv;
    }
    __syncthreads();
    if (t < NPG) {
      float e = 0.f;
#pragma unroll
      for (int j4 = 0; j4 < 16; ++j4) {
        float4 a = *(const float4*)&hs[t][j4 * 4];
        float4 b = *(const float4*)&hls[j4 * 4];
        e += a.x * b.x + a.y * b.y + a.z * b.z + a.w * b.w;
      }
      es_s[t] = e;
    }
    __syncthreads();
    if (t < 64) {
      float mx = -1e30f;
#pragma unroll
      for (int rr = 0; rr < NPG; ++rr) mx = fmaxf(mx, es_s[rr]);
      float sm = 0.f, rv = 0.f;
#pragma unroll
      for (int rr = 0; rr < NPG; ++rr) {
        float ex = expf(es_s[rr] - mx);
        sm += ex;
        rv += ex * hs[rr][t];
      }
      qstar[DIMH + t] = rv / sm;
    }
    __syncthreads();
  }
  if (t < 64) {
    float acc = l1b[t];
    for (int j = 0; j < 2 * DIMH; ++j) acc += qstar[j] * l1w[j * DIMH + t];
    float v = fmaxf(acc, 0.f) * l2w[t];
    for (int off = 32; off > 0; off >>= 1) v += __shfl_down(v, off);
    if (t == 0) y[g] = v + l2b[0];
  }
}

extern "C" void kernel_launch(void* const* d_in, const int* in_sizes, int n_in,
                              void* d_out, int out_size, void* d_ws, size_t ws_size,
                              hipStream_t stream) {
  const float* x     = (const float*)d_in[0];
  const float* ea    = (const float*)d_in[2];
  const float* lin0w = (const float*)d_in[4];
  const float* lin0b = (const float*)d_in[5];
  const float* nn1w  = (const float*)d_in[6];
  const float* nn1b  = (const float*)d_in[7];
  const float* nn2w  = (const float*)d_in[8];
  const float* nn2b  = (const float*)d_in[9];
  const float* rootw = (const float*)d_in[10];
  const float* convb = (const float*)d_in[11];
  const float* gwih  = (const float*)d_in[12];
  const float* gwhh  = (const float*)d_in[13];
  const float* gbih  = (const float*)d_in[14];
  const float* gbhh  = (const float*)d_in[15];
  const float* lwih  = (const float*)d_in[16];
  const float* lwhh  = (const float*)d_in[17];
  const float* lbih  = (const float*)d_in[18];
  const float* lbhh  = (const float*)d_in[19];
  const float* l1w   = (const float*)d_in[20];
  const float* l1b   = (const float*)d_in[21];
  const float* l2w   = (const float*)d_in[22];
  const float* l2b   = (const float*)d_in[23];
  float* yout = (float*)d_out;

  // workspace layout (bytes)
  char* ws = (char*)d_ws;
  float*    out  = (float*)ws;                   // 655360
  _Float16* h1c  = (_Float16*)(ws + 655360);     // 12451840
  _Float16* WT2  = (_Float16*)(ws + 13107200);   // 1048576
  _Float16* WpT2 = (_Float16*)(ws + 14155776);   // 8192
  float*    bgc  = (float*)(ws + 14163968);      // 32768
  _Float16* part = (_Float16*)(ws + 14196736);   // 16*2560*64*2 = 5242880
  float*    wab  = (float*)(ws + 19439616);      // 256*128*4 = 131072
  (void)ws_size; (void)in_sizes; (void)n_in; (void)out_size;

  k_prep<<<1230, 256, 0, stream>>>(x, lin0w, lin0b, ea, nn1w, nn1b,
                                   nn2w, nn2b, rootw, lwih, lwhh,
                                   out, h1c, WT2, WpT2, wab);
  for (int it = 0; it < 3; ++it) {
    k_pg<<<dim3(NCH, NG), 256, 0, stream>>>(h1c, out, WT2, WpT2, nn2b, convb,
                                            bgc, part);
    k_gru<<<NG * 2, 512, 0, stream>>>(part, bgc, gwih, gwhh, gbih, gbhh, out);
  }
  k_s2s<<<NG, 256, 0, stream>>>(out, wab, lbih, lbhh,
                                l1w, l1b, l2w, l2b, yout);
}

// Round 22
// 125.154 us; speedup vs baseline: 1.4438x; 1.4438x over previous
//
#include <hip/hip_runtime.h>
#include <hip/hip_fp16.h>

// ---- problem constants (fixed by setup_inputs) ----
#define DIMH 64
#define NFEAT 11
#define EFEAT 5
#define NG   128
#define NPG  20
#define NNODES (NG*NPG)        // 2560
#define EPG  (NPG*(NPG-1))     // 380
#define NEDGES (NG*EPG)        // 48640
#define H1D  128
#define KTOT (H1D*DIMH)        // 8192
#define DEGV 19.0f
#define NCH  16                // part chunks (one per k-octet)

typedef __attribute__((ext_vector_type(8))) _Float16 f16x8;
typedef __attribute__((ext_vector_type(4))) float    f32x4;

// ---------------------------------------------------------------------------
// k_prep: prologue jobs (grid 1230).  (R20 champion, verbatim)
// ---------------------------------------------------------------------------
__global__ __launch_bounds__(256) void k_prep(
    const float* __restrict__ x, const float* __restrict__ lin0w,
    const float* __restrict__ lin0b,
    const float* __restrict__ ea, const float* __restrict__ nn1w,
    const float* __restrict__ nn1b,
    const float* __restrict__ nn2w, const float* __restrict__ nn2b,
    const float* __restrict__ rootw,
    const float* __restrict__ lwih, const float* __restrict__ lwhh,
    float* __restrict__ out, _Float16* __restrict__ h1c,
    _Float16* __restrict__ WT2, _Float16* __restrict__ WpT2,
    float* __restrict__ wab) {
  int b = blockIdx.x, t = threadIdx.x;
  if (b < 256) {
    int tid = b * 256 + t;                 // 0..65535
    int ko = tid >> 12, ks = (tid >> 8) & 15, nf = (tid >> 6) & 3, l = tid & 63;
    int i = ks * 4 + (l >> 4);
    int o = nf * 16 + (l & 15);
    const float* src = nn2w + (size_t)(ko * 8) * 4096 + i * 64 + o;
    f16x8 v;
#pragma unroll
    for (int j = 0; j < 8; ++j)
      v[j] = (_Float16)(src[(size_t)j * 4096] * (1.f / DEGV));
    *(f16x8*)(WT2 + (size_t)tid * 8) = v;
  } else if (b < 896) {
    int idx = (b - 256) * 256 + t;
    int n = idx >> 6, o = idx & 63;
    float acc = lin0b[o];
#pragma unroll
    for (int j = 0; j < NFEAT; ++j) acc += x[n * NFEAT + j] * lin0w[j * DIMH + o];
    out[idx] = fmaxf(acc, 0.f);
  } else if (b < 1086) {
    int e = (b - 896) * 256 + t;
    float ef[EFEAT];
#pragma unroll
    for (int f = 0; f < EFEAT; ++f) ef[f] = ea[e * EFEAT + f];
    for (int ko = 0; ko < 16; ++ko) {
      f16x8 hv;
#pragma unroll
      for (int j = 0; j < 8; ++j) {
        int k = ko * 8 + j;
        float acc = nn1b[k];
#pragma unroll
        for (int f = 0; f < EFEAT; ++f) acc += ef[f] * nn1w[f * H1D + k];
        hv[j] = (_Float16)fmaxf(acc, 0.f);
      }
      ((f16x8*)h1c)[(size_t)ko * NEDGES + e] = hv;
    }
  } else if (b < 1102) {
    int idx = (b - 1086) * 256 + t;      // 0..4095
    int jp = idx & 7, l = (idx >> 3) & 63, nf = (idx >> 9) & 3;
    int ks = (idx >> 11) & 1;
    int o = nf * 16 + (l & 15);
    int j = ks * 32 + (l >> 4) * 8 + jp;
    WpT2[idx] = (_Float16)(rootw[j * 64 + o] - nn2b[j * 64 + o] * (1.f / DEGV));
  } else {
    int idx = (b - 1102) * 256 + t;      // 0..32767
    int row = idx >> 7, col = idx & 127;
    float v = lwih[(size_t)row * 128 + col];
    if (col < 64) v += lwhh[(size_t)row * 64 + col];
    wab[idx] = v;
  }
}

// ---------------------------------------------------------------------------
// k_pg: fused P-build + MFMA GEMM.  block = (ko, g).  (R20 champion: LDS
// h1 staging + wave=nf B-dedup MFMA + packed fp16 P-build + fp16 part.)
// ---------------------------------------------------------------------------
__global__ __launch_bounds__(256, 4) void k_pg(const _Float16* __restrict__ h1c,
                                               const float* __restrict__ out,
                                               const _Float16* __restrict__ WT2,
                                               const _Float16* __restrict__ WpT2,
                                               const float* __restrict__ nn2b,
                                               const float* __restrict__ convb,
                                               float* __restrict__ bgc,
                                               _Float16* __restrict__ part) {
  int ko = blockIdx.x, g = blockIdx.y;
  int t = threadIdx.x;
  __shared__ alignas(16) f16x8 h1s[EPG];
  __shared__ alignas(16) _Float16 Ps[NPG][520];
  __shared__ float sgl[64];
  __shared__ alignas(16) _Float16 AoT[NPG][64];
  int i = t & 63, w = t >> 6;
  int la = i & 15, hi = i >> 4;
  int nf = w;                              // wave = output column block
  _Float16 xh[NPG];
  {
    float s = 0.f;
#pragma unroll
    for (int r = 0; r < NPG; ++r) {
      float xv = out[((size_t)g * NPG + r) * 64 + i];
      s += xv;
      xh[r] = (_Float16)xv;
    }
    if (ko == 0 && t < 64) sgl[t] = s;
  }
  {
    const f16x8* src = (const f16x8*)h1c + ((size_t)ko * NEDGES + (size_t)g * EPG);
    for (int el = t; el < EPG; el += 256) h1s[el] = src[el];
  }
  __syncthreads();
  if (ko == 0 && t < 64) {      // bgc = sg . b2/19 + convb   (serial in wave 0)
    float acc = convb[t];
    for (int ii = 0; ii < 64; ++ii)
      acc += sgl[ii] * nn2b[ii * 64 + t] * (1.f / DEGV);
    bgc[g * 64 + t] = acc;
  }
  {
#pragma unroll
    for (int cc = 0; cc < 5; ++cc) {
      int c = w + cc * 4;
      f16x8 acc = {(_Float16)0.f, (_Float16)0.f, (_Float16)0.f, (_Float16)0.f,
                   (_Float16)0.f, (_Float16)0.f, (_Float16)0.f, (_Float16)0.f};
#pragma unroll
      for (int r = 0; r < NPG; ++r) {
        if (r == c) continue;                 // wave-uniform skip
        int el = r * 19 + c - (c > r ? 1 : 0);
        acc += h1s[el] * xh[r];               // packed v_pk_fma_f16
      }
      *(f16x8*)&Ps[c][i * 8] = acc;           // direct b128 store, no cvt
    }
  }
  __syncthreads();
  f32x4 acc0 = {0.f, 0.f, 0.f, 0.f};   // tile0: A rows la    (writes rows 0..3)
  f32x4 acc1 = {0.f, 0.f, 0.f, 0.f};   // tile1: A rows 4+la  (writes rows 4..19)
  const f16x8* B = (const f16x8*)WT2;
#pragma unroll
  for (int ks = 0; ks < 16; ++ks) {
    f16x8 b0 = B[(size_t)(((ko * 16 + ks) * 4 + nf) * 64 + i)];
    f16x8 a0 = *(const f16x8*)&Ps[la][(ks * 4 + hi) * 8];
    f16x8 a1 = *(const f16x8*)&Ps[4 + la][(ks * 4 + hi) * 8];
    acc0 = __builtin_amdgcn_mfma_f32_16x16x32_f16(a0, b0, acc0, 0, 0, 0);
    acc1 = __builtin_amdgcn_mfma_f32_16x16x32_f16(a1, b0, acc1, 0, 0, 0);
  }
  if (ko == 15) {               // fold root term: A = fp16(out rows), B = WpT2
    if (w == 0) {
#pragma unroll
      for (int r = 0; r < NPG; ++r) AoT[r][i] = xh[r];
    }
    __syncthreads();
    const f16x8* W2f = (const f16x8*)WpT2;
#pragma unroll
    for (int ks2 = 0; ks2 < 2; ++ks2) {
      f16x8 b0 = W2f[(size_t)((ks2 * 4 + nf) * 64 + i)];
      f16x8 a0 = *(const f16x8*)&AoT[la][ks2 * 32 + hi * 8];
      f16x8 a1 = *(const f16x8*)&AoT[4 + la][ks2 * 32 + hi * 8];
      acc0 = __builtin_amdgcn_mfma_f32_16x16x32_f16(a0, b0, acc0, 0, 0, 0);
      acc1 = __builtin_amdgcn_mfma_f32_16x16x32_f16(a1, b0, acc1, 0, 0, 0);
    }
  }
  if (hi == 0) {                // tile0: rows 0..3, cols nf*16+la
#pragma unroll
    for (int q = 0; q < 4; ++q) {
      size_t base = ((size_t)(g * NPG + q) * NCH + ko) * 64;
      part[base + nf * 16 + la] = (_Float16)acc0[q];
    }
  }
#pragma unroll
  for (int q = 0; q < 4; ++q) { // tile1: rows 4..19, cols nf*16+la
    int row = 4 + hi * 4 + q;
    size_t base = ((size_t)(g * NPG + row) * NCH + ko) * 64;
    part[base + nf * 16 + la] = (_Float16)acc1[q];
  }
}

// ---------------------------------------------------------------------------
// k_gru: fused part-reduce + GRU, split 2 blocks per graph (node-local).
// 256 blocks x 512 threads, 10 nodes each.  (R20 champion, verbatim)
// ---------------------------------------------------------------------------
#define NLOC 10
__global__ __launch_bounds__(512, 1) void k_gru(
    const _Float16* __restrict__ part, const float* __restrict__ bgc,
    const float* __restrict__ wih, const float* __restrict__ whh,
    const float* __restrict__ bih, const float* __restrict__ bhh,
    float* __restrict__ out) {
  __shared__ float outs[NLOC][64];
  __shared__ float ms[NLOC][64];
  __shared__ float gi_s[NLOC][192];
  __shared__ float gh_s[NLOC][192];
  int t = threadIdx.x;
  int b = blockIdx.x, g = b >> 1, nbase = (b & 1) * NLOC;
  int role = (t < 192) ? 0 : ((t >= 256 && t < 448) ? 1 : -1);
  int r = (t < 192) ? t : t - 256;
  float4 wreg[16];
  if (role == 0) {
    const float4* src = (const float4*)(wih + (size_t)r * 64);
#pragma unroll
    for (int q = 0; q < 16; ++q) wreg[q] = src[q];
  } else if (role == 1) {
    const float4* src = (const float4*)(whh + (size_t)r * 64);
#pragma unroll
    for (int q = 0; q < 16; ++q) wreg[q] = src[q];
  }
  if (t < NLOC * 16)
    ((float4*)&outs[0][0])[t] =
        ((const float4*)(out + ((size_t)g * NPG + nbase) * 64))[t];
  __syncthreads();
  int o = t & 63, n0 = t >> 6;
  {
    float base = bgc[g * 64 + o];
#pragma unroll
    for (int k = 0; k < 2; ++k) {
      int n = n0 + k * 8;
      if (n < NLOC) {
        float a = base;
#pragma unroll
        for (int c = 0; c < NCH; ++c)
          a += (float)part[((size_t)(g * NPG + nbase + n) * NCH + c) * 64 + o];
        ms[n][o] = fmaxf(a, 0.f);
      }
    }
  }
  __syncthreads();
  if (role == 0) {
    for (int n = 0; n < NLOC; ++n) {
      float acc = 0.f;
#pragma unroll
      for (int q = 0; q < 16; ++q) {
        float4 xv = *(const float4*)&ms[n][q * 4];
        acc += wreg[q].x * xv.x + wreg[q].y * xv.y +
               wreg[q].z * xv.z + wreg[q].w * xv.w;
      }
      gi_s[n][r] = acc;
    }
  } else if (role == 1) {
    for (int n = 0; n < NLOC; ++n) {
      float acc = 0.f;
#pragma unroll
      for (int q = 0; q < 16; ++q) {
        float4 xv = *(const float4*)&outs[n][q * 4];
        acc += wreg[q].x * xv.x + wreg[q].y * xv.y +
               wreg[q].z * xv.z + wreg[q].w * xv.w;
      }
      gh_s[n][r] = acc;
    }
  }
  __syncthreads();
  {
    float bir = bih[o], biz = bih[64 + o], bin = bih[128 + o];
    float bhr = bhh[o], bhz = bhh[64 + o], bhn = bhh[128 + o];
#pragma unroll
    for (int k = 0; k < 2; ++k) {
      int n = n0 + k * 8;
      if (n < NLOC) {
        float rr = 1.f / (1.f + expf(-(gi_s[n][o] + bir + gh_s[n][o] + bhr)));
        float zz = 1.f / (1.f + expf(-(gi_s[n][64 + o] + biz +
                                       gh_s[n][64 + o] + bhz)));
        float nc = tanhf(gi_s[n][128 + o] + bin +
                         rr * (gh_s[n][128 + o] + bhn));
        out[((size_t)g * NPG + nbase + n) * DIMH + o] =
            (1.f - zz) * nc + zz * outs[n][o];
      }
    }
  }
}

// ---------------------------------------------------------------------------
// k_s2s: Set2Set (3 steps) + final MLP, 256 threads / graph.
// (R20 champion, verbatim)
// ---------------------------------------------------------------------------
__global__ __launch_bounds__(256) void k_s2s(
    const float* __restrict__ hn,
    const float* __restrict__ wab,
    const float* __restrict__ lbih, const float* __restrict__ lbhh,
    const float* __restrict__ l1w, const float* __restrict__ l1b,
    const float* __restrict__ l2w, const float* __restrict__ l2b,
    float* __restrict__ y) {
  int g = blockIdx.x, t = threadIdx.x;
  __shared__ float hs[NPG][DIMH];
  __shared__ float qstar[2 * DIMH];
  __shared__ float hls[DIMH];
  __shared__ float es_s[NPG];
  __shared__ float gates_s[4][DIMH];
  for (int idx = t; idx < NPG * 16; idx += 256)
    ((float4*)&hs[0][0])[idx] = ((const float4*)(hn + (size_t)g * NPG * 64))[idx];
  if (t < 128) qstar[t] = 0.f;
  if (t < 64) hls[t] = 0.f;
  float cl = 0.f;
  __syncthreads();
  int q = t >> 6, o = t & 63;
  const float4* wa = (const float4*)(wab + (size_t)(q * 64 + o) * 128);
  float bsum = lbih[q * 64 + o] + lbhh[q * 64 + o];
  for (int step = 0; step < 3; ++step) {
    {
      float acc = bsum;
      if (step > 0) {            // step 0: qstar = hls = 0 -> dots vanish
#pragma unroll
        for (int j4 = 0; j4 < 16; ++j4) {       // (Wih[:,:64]+Whh) . hl
          float4 w = wa[j4];
          float4 xv = *(const float4*)&hls[j4 * 4];
          acc += w.x * xv.x + w.y * xv.y + w.z * xv.z + w.w * xv.w;
        }
#pragma unroll
        for (int j4 = 0; j4 < 16; ++j4) {       // Wih[:,64:] . rvec
          float4 w = wa[16 + j4];
          float4 xv = *(const float4*)&qstar[DIMH + j4 * 4];
          acc += w.x * xv.x + w.y * xv.y + w.z * xv.z + w.w * xv.w;
        }
      }
      gates_s[q][o] = acc;
    }
    __syncthreads();
    if (t < 64) {
      float gi = gates_s[0][t], gf = gates_s[1][t];
      float gg = gates_s[2][t], go = gates_s[3][t];
      cl = 1.f / (1.f + expf(-gf)) * cl + 1.f / (1.f + expf(-gi)) * tanhf(gg);
      float hv = 1.f / (1.f + expf(-go)) * tanhf(cl);
      hls[t] = hv; qstar[t] = hv;
    }
    __syncthreads();
    if (t < NPG) {
      float e = 0.f;
#pragma unroll
      for (int j4 = 0; j4 < 16; ++j4) {
        float4 a = *(const float4*)&hs[t][j4 * 4];
        float4 b = *(const float4*)&hls[j4 * 4];
        e += a.x * b.x + a.y * b.y + a.z * b.z + a.w * b.w;
      }
      es_s[t] = e;
    }
    __syncthreads();
    if (t < 64) {
      float mx = -1e30f;
#pragma unroll
      for (int rr = 0; rr < NPG; ++rr) mx = fmaxf(mx, es_s[rr]);
      float sm = 0.f, rv = 0.f;
#pragma unroll
      for (int rr = 0; rr < NPG; ++rr) {
        float ex = expf(es_s[rr] - mx);
        sm += ex;
        rv += ex * hs[rr][t];
      }
      qstar[DIMH + t] = rv / sm;
    }
    __syncthreads();
  }
  if (t < 64) {
    float acc = l1b[t];
    for (int j = 0; j < 2 * DIMH; ++j) acc += qstar[j] * l1w[j * DIMH + t];
    float v = fmaxf(acc, 0.f) * l2w[t];
    for (int off = 32; off > 0; off >>= 1) v += __shfl_down(v, off);
    if (t == 0) y[g] = v + l2b[0];
  }
}

extern "C" void kernel_launch(void* const* d_in, const int* in_sizes, int n_in,
                              void* d_out, int out_size, void* d_ws, size_t ws_size,
                              hipStream_t stream) {
  const float* x     = (const float*)d_in[0];
  const float* ea    = (const float*)d_in[2];
  const float* lin0w = (const float*)d_in[4];
  const float* lin0b = (const float*)d_in[5];
  const float* nn1w  = (const float*)d_in[6];
  const float* nn1b  = (const float*)d_in[7];
  const float* nn2w  = (const float*)d_in[8];
  const float* nn2b  = (const float*)d_in[9];
  const float* rootw = (const float*)d_in[10];
  const float* convb = (const float*)d_in[11];
  const float* gwih  = (const float*)d_in[12];
  const float* gwhh  = (const float*)d_in[13];
  const float* gbih  = (const float*)d_in[14];
  const float* gbhh  = (const float*)d_in[15];
  const float* lwih  = (const float*)d_in[16];
  const float* lwhh  = (const float*)d_in[17];
  const float* lbih  = (const float*)d_in[18];
  const float* lbhh  = (const float*)d_in[19];
  const float* l1w   = (const float*)d_in[20];
  const float* l1b   = (const float*)d_in[21];
  const float* l2w   = (const float*)d_in[22];
  const float* l2b   = (const float*)d_in[23];
  float* yout = (float*)d_out;

  // workspace layout (bytes)
  char* ws = (char*)d_ws;
  float*    out  = (float*)ws;                   // 655360
  _Float16* h1c  = (_Float16*)(ws + 655360);     // 12451840
  _Float16* WT2  = (_Float16*)(ws + 13107200);   // 1048576
  _Float16* WpT2 = (_Float16*)(ws + 14155776);   // 8192
  float*    bgc  = (float*)(ws + 14163968);      // 32768
  _Float16* part = (_Float16*)(ws + 14196736);   // 16*2560*64*2 = 5242880
  float*    wab  = (float*)(ws + 19439616);      // 256*128*4 = 131072
  (void)ws_size; (void)in_sizes; (void)n_in; (void)out_size;

  k_prep<<<1230, 256, 0, stream>>>(x, lin0w, lin0b, ea, nn1w, nn1b,
                                   nn2w, nn2b, rootw, lwih, lwhh,
                                   out, h1c, WT2, WpT2, wab);
  for (int it = 0; it < 3; ++it) {
    k_pg<<<dim3(NCH, NG), 256, 0, stream>>>(h1c, out, WT2, WpT2, nn2b, convb,
                                            bgc, part);
    k_gru<<<NG * 2, 512, 0, stream>>>(part, bgc, gwih, gwhh, gbih, gbhh, out);
  }
  k_s2s<<<NG, 256, 0, stream>>>(out, wab, lbih, lbhh,
                                l1w, l1b, l2w, l2b, yout);
}